// Round 6
// baseline (508.275 us; speedup 1.0000x reference)
//
#include <hip/hip_runtime.h>
#include <math.h>
#include <stdint.h>

#define TOK 65536
#define DIN 256
#define EDIM 512
#define KCB 2048
#define NTA 4096        // A m-tiles (65536/16)
#define NTB 128         // B n-tiles (2048/16)

// workspace layout (float offsets), 64-float aligned
#define OFF_MP   0u                     // M' fp32 [2048*256]
#define OFF_CP   524288u                // c' [2048]
#define OFF_Q    526336u                // Q [2048*256]
#define OFF_W2T  1050624u               // W2T [512*256]
#define OFF_U    1181696u               // u [512]
#define OFF_CQ   1182208u               // cQ [256]
#define OFF_PV   1182464u               // partial vals [16][65536] (transposed)
#define OFF_PI   2231040u               // partial idx  [16][65536]
#define OFF_AH   3279616u               // A packed bf16 [8][4096][512]
#define OFF_BH   11668224u              // B packed bf16 [8][128][512]
#define TOT_F    11930368u

typedef short short8 __attribute__((ext_vector_type(8)));
typedef float f32x4 __attribute__((ext_vector_type(4)));

__device__ __forceinline__ unsigned short bf16rne(float x) {
    uint32_t u = __float_as_uint(x);
    u += 0x7fffu + ((u >> 16) & 1u);
    return (unsigned short)(u >> 16);
}
__device__ __forceinline__ void async_load16(const void* g, void* l) {
    __builtin_amdgcn_global_load_lds((const __attribute__((address_space(1))) void*)g,
                                     (__attribute__((address_space(3))) void*)l, 16, 0, 0);
}

// fused: zero loss scalar + usage bins, then prep1 work.
// blocks 0..511: e -> W2T[e][o], u[e];  512..767: o -> cQ[o]
__global__ void prep1_kernel(const float* __restrict__ W1, const float* __restrict__ W2,
                             const float* __restrict__ bn1_beta, const float* __restrict__ bn2_gamma,
                             const float* __restrict__ bn2_beta, const float* __restrict__ b2,
                             float* __restrict__ W2T, float* __restrict__ u, float* __restrict__ cQ,
                             float* __restrict__ out) {
    __shared__ float red[256];
    const int b = blockIdx.x, t = threadIdx.x;
    const int gid = b * 256 + t;
    if (gid == 0) out[0] = 0.0f;
    if (gid < KCB) out[1 + TOK * DIN + gid] = 0.0f;
    const float s = 1.0f / sqrtf(1.0f + 1e-5f);
    if (b < EDIM) {
        int e = b;
        W2T[e * DIN + t] = bn2_gamma[e] * s * W2[t * EDIM + e];
        float v = bn1_beta[t] * W1[e * DIN + t];
        red[t] = v; __syncthreads();
        for (int off = 128; off; off >>= 1) { if (t < off) red[t] += red[t + off]; __syncthreads(); }
        if (t == 0) u[e] = red[0];
    } else {
        int o = b - EDIM;
        float v = bn2_beta[t] * W2[o * EDIM + t] + bn2_beta[t + 256] * W2[o * EDIM + t + 256];
        red[t] = v; __syncthreads();
        for (int off = 128; off; off >>= 1) { if (t < off) red[t] += red[t + off]; __syncthreads(); }
        if (t == 0) cQ[o] = b2[o] + red[0];
    }
}

// per block: 8 codebook rows, E-tile in LDS, W streamed from L2 once per block.
__global__ __launch_bounds__(256) void prep2_kernel(const float* __restrict__ E, const float* __restrict__ W1,
                                                    const float* __restrict__ W2T, const float* __restrict__ bn1_gamma,
                                                    const float* __restrict__ cQ,
                                                    float* __restrict__ Mp, float* __restrict__ Q) {
    __shared__ float Elds[8 * EDIM]; // [r][e] 16 KB
    const int k0 = blockIdx.x * 8, t = threadIdx.x;
    const float4* src = (const float4*)(E + (size_t)k0 * EDIM);
    float4* dst = (float4*)Elds;
#pragma unroll
    for (int i = 0; i < 4; i++) dst[i * 256 + t] = src[i * 256 + t];
    __syncthreads();
    float m[8] = {0, 0, 0, 0, 0, 0, 0, 0};
    float q[8] = {0, 0, 0, 0, 0, 0, 0, 0};
    for (int e = 0; e < EDIM; e++) {
        float w1 = W1[e * DIN + t];
        float w2 = W2T[e * DIN + t];
#pragma unroll
        for (int r = 0; r < 8; r++) {
            float ev = Elds[r * EDIM + e];   // same-address broadcast, conflict-free
            m[r] += ev * w1; q[r] += ev * w2;
        }
    }
    const float s = 1.0f / sqrtf(1.0f + 1e-5f);
    const float gs = bn1_gamma[t] * s;
    const float cq = cQ[t];
#pragma unroll
    for (int r = 0; r < 8; r++) {
        Mp[(size_t)(k0 + r) * DIN + t] = gs * m[r];
        Q[(size_t)(k0 + r) * DIN + t] = q[r] + cq;
    }
}

// c'[k] = sum_e E[k][e]*(b1[e]+u[e]) - 0.5*sum_e E[k][e]^2 ; one wave per row
__global__ __launch_bounds__(256) void prep3_kernel(const float* __restrict__ E, const float* __restrict__ b1,
                                                    const float* __restrict__ u, float* __restrict__ cp) {
    const int t = threadIdx.x, lane = t & 63;
    const int k = blockIdx.x * 4 + (t >> 6);
    const float4* er = (const float4*)(E + (size_t)k * EDIM);
    float sa = 0.0f, sb = 0.0f;
#pragma unroll
    for (int i = 0; i < 2; i++) {
        int j4 = lane * 2 + i;
        float4 ev = er[j4];
        int e = j4 * 4;
        sa += ev.x * (b1[e] + u[e]) + ev.y * (b1[e + 1] + u[e + 1])
            + ev.z * (b1[e + 2] + u[e + 2]) + ev.w * (b1[e + 3] + u[e + 3]);
        sb += ev.x * ev.x + ev.y * ev.y + ev.z * ev.z + ev.w * ev.w;
    }
    float v = sa - 0.5f * sb;
#pragma unroll
    for (int off = 32; off; off >>= 1) v += __shfl_down(v, off, 64);
    if (lane == 0) cp[k] = v;
}

// X[R x 256] fp32 -> bf16 in MFMA fragment-tile order:
// plane kc (0..7), tile tt (16 rows), 1KB block: lane L owns
// X[tt*16 + (L&15)][kc*32 + (L>>4)*8 + 0..7].
__global__ __launch_bounds__(256) void pack_kernel(const float* __restrict__ X,
                                                   unsigned short* __restrict__ Hp, int ntiles) {
    __shared__ __align__(16) unsigned short Hs[32 * 264];
    const int t = threadIdx.x;
    const int r0 = blockIdx.x * 32;
    const float4* src = (const float4*)(X + (size_t)r0 * DIN);
#pragma unroll
    for (int i = 0; i < 8; i++) {
        int id = i * 256 + t;
        int row = id >> 6, c4 = id & 63;
        float4 v = src[id];
        float f[4] = {v.x, v.y, v.z, v.w};
        ushort4 H;
        unsigned short* hp = (unsigned short*)&H;
#pragma unroll
        for (int j = 0; j < 4; j++) hp[j] = bf16rne(f[j]);
        *(ushort4*)&Hs[row * 264 + c4 * 4] = H;
    }
    __syncthreads();
    const int lane = t & 63, w = t >> 6;
#pragma unroll
    for (int q = 0; q < 4; q++) {
        int fb = q * 4 + w;              // 0..15
        int tl = fb >> 3, kc = fb & 7;
        int srow = tl * 16 + (lane & 15);
        int scol = kc * 32 + (lane >> 4) * 8;
        short8 vh = *(const short8*)&Hs[srow * 264 + scol];
        size_t off = ((size_t)kc * ntiles + (r0 >> 4) + tl) * 512 + lane * 8;
        *(short8*)&Hp[off] = vh;
    }
}

// MFMA scorer: A-tile (64 KB, full K) staged to LDS once via global_load_lds,
// ONE barrier per block, then barrier-free K-loop: ds_read af + double-buffered
// direct global bf (B L2-resident everywhere) + 16 MFMA per kc.
// XCD-swizzled grid; pval/pidx transposed [nb][m].
__global__ __launch_bounds__(256) void score_mfma_kernel(const unsigned short* __restrict__ Ah,
                                                         const unsigned short* __restrict__ Bh,
                                                         const float* __restrict__ cp,
                                                         float* __restrict__ pval, int* __restrict__ pidx) {
    __shared__ __align__(16) unsigned short Alds[8 * 8 * 512];  // 64 KB: [kc][mt][512]
    __shared__ float ev[2 * 128];
    __shared__ int   ei[2 * 128];
    const int t = threadIdx.x, lane = t & 63, w = t >> 6;
    const int wm = w & 1, wn = w >> 1;
    const int b = blockIdx.x;
    const int nb = (b >> 3) & 15;                 // xcd = b&7 round-robin heuristic
    const int mb = (b & 7) + ((b >> 7) << 3);     // all 16 nb of an mb -> same xcd
    const int m0 = mb * 128;
    const int n0 = nb * 128;
    const int mt0 = m0 >> 4;
    const int bnt = nb * 8 + wn * 4;

    // stage A: wave w stages kc = 2w and 2w+1 (8 tiles each, 1 KB per load)
#pragma unroll
    for (int kk = 0; kk < 2; kk++) {
        int kc = 2 * w + kk;
        const unsigned short* gs = Ah + ((size_t)kc * NTA + mt0) * 512 + lane * 8;
        unsigned short* ld = &Alds[kc * 8 * 512];
#pragma unroll
        for (int mt = 0; mt < 8; mt++)
            async_load16(gs + mt * 512, ld + mt * 512);
    }

    const short8* B8 = (const short8*)Bh;   // frag = B8[(kc*NTB + tile)*64 + lane]
    short8 bf[2][4];
#pragma unroll
    for (int nt = 0; nt < 4; nt++)
        bf[0][nt] = B8[((size_t)0 * NTB + bnt + nt) * 64 + lane];

    f32x4 acc[4][4];
#pragma unroll
    for (int i = 0; i < 4; i++)
#pragma unroll
        for (int j = 0; j < 4; j++) acc[i][j] = (f32x4){0.f, 0.f, 0.f, 0.f};

    __syncthreads();   // A staged (vmcnt drain includes bf[0]); only barrier in K-path

#pragma unroll
    for (int kc = 0; kc < 8; kc++) {
        const int cur = kc & 1, nxt = cur ^ 1;
        if (kc < 7) {
#pragma unroll
            for (int nt = 0; nt < 4; nt++)
                bf[nxt][nt] = B8[((size_t)(kc + 1) * NTB + bnt + nt) * 64 + lane];
        }
        short8 af[4];
#pragma unroll
        for (int mt = 0; mt < 4; mt++)
            af[mt] = *(const short8*)&Alds[(kc * 8 + wm * 4 + mt) * 512 + lane * 8];
#pragma unroll
        for (int mt = 0; mt < 4; mt++)
#pragma unroll
            for (int nt = 0; nt < 4; nt++)
                acc[mt][nt] = __builtin_amdgcn_mfma_f32_16x16x32_bf16(af[mt], bf[cur][nt], acc[mt][nt], 0, 0, 0);
    }

    // epilogue: add c', argmax over this block's 128 codes per row
    const int fr = lane & 15;
    const int colb = n0 + wn * 64 + fr;
    float cpv[4];
#pragma unroll
    for (int nt = 0; nt < 4; nt++) cpv[nt] = cp[colb + nt * 16];
#pragma unroll
    for (int mt = 0; mt < 4; mt++) {
#pragma unroll
        for (int r = 0; r < 4; r++) {
            float bv = acc[mt][0][r] + cpv[0];
            int bc = colb;
#pragma unroll
            for (int nt = 1; nt < 4; nt++) {
                float v = acc[mt][nt][r] + cpv[nt];
                if (v > bv) { bv = v; bc = colb + nt * 16; }
            }
#pragma unroll
            for (int xm = 1; xm < 16; xm <<= 1) {
                float ov = __shfl_xor(bv, xm, 64);
                int oc = __shfl_xor(bc, xm, 64);
                if (ov > bv || (ov == bv && oc < bc)) { bv = ov; bc = oc; }
            }
            if (fr == 0) {
                int row = wm * 64 + mt * 16 + ((lane >> 4) << 2) + r;
                ev[wn * 128 + row] = bv;
                ei[wn * 128 + row] = bc;
            }
        }
    }
    __syncthreads();
    if (t < 128) {
        float v0 = ev[t]; int c0 = ei[t];
        float v1 = ev[128 + t]; int c1 = ei[128 + t];
        if (v1 > v0) { v0 = v1; c0 = c1; }   // wn=1 cols strictly higher -> strict >
        pval[(size_t)nb * TOK + m0 + t] = v0;
        pidx[(size_t)nb * TOK + m0 + t] = c0;
    }
}

// gather: block stages its 256 rows' 16 partials into LDS (coalesced),
// per-thread reduce, then coalesced Q-gather + output + loss + usage.
__global__ __launch_bounds__(256) void gather_out_kernel(const float* __restrict__ flat,
                                                         const float* __restrict__ Q,
                                                         const float* __restrict__ pval,
                                                         const int* __restrict__ pidx,
                                                         float* __restrict__ out) {
    __shared__ float pv[16 * 256];
    __shared__ int   pi[16 * 256];
    __shared__ int   ksel[256];
    const int t = threadIdx.x;
    const int r0 = blockIdx.x * 256;
#pragma unroll
    for (int j = 0; j < 16; j++) {
        pv[j * 256 + t] = pval[(size_t)j * TOK + r0 + t];
        pi[j * 256 + t] = pidx[(size_t)j * TOK + r0 + t];
    }
    __syncthreads();
    {
        float bv = pv[t]; int bc = pi[t];
#pragma unroll
        for (int j = 1; j < 16; j++) {
            float v = pv[j * 256 + t]; int c = pi[j * 256 + t];
            if (v > bv || (v == bv && c < bc)) { bv = v; bc = c; }
        }
        ksel[t] = bc;
    }
    __syncthreads();
    const int lane = t & 63, w = t >> 6;
    float lsum = 0.0f;
    for (int rr = 0; rr < 64; rr++) {
        int lr = w * 64 + rr;
        int row = r0 + lr;
        int k = ksel[lr];
        const float* qr = Q + (size_t)k * DIN;
        const float* xr = flat + (size_t)row * DIN;
        float* ob = out + 1 + (size_t)row * DIN;
#pragma unroll
        for (int cc = 0; cc < 4; cc++) {
            int j = lane + 64 * cc;
            float q = qr[j];
            float d = q - xr[j];
            lsum += d * d;
            ob[j] = q;
        }
        if (lane == 0) atomicAdd(out + 1 + TOK * DIN + k, 1.0f / (float)TOK);
    }
#pragma unroll
    for (int off = 32; off; off >>= 1) lsum += __shfl_down(lsum, off, 64);
    if (lane == 0) atomicAdd(out, lsum * (1.25f / (float)((size_t)TOK * DIN)));
}

extern "C" void kernel_launch(void* const* d_in, const int* in_sizes, int n_in,
                              void* d_out, int out_size, void* d_ws, size_t ws_size,
                              hipStream_t stream) {
    const float* inputs = (const float*)d_in[0];
    const float* bn1_gamma = (const float*)d_in[1];
    const float* bn1_beta  = (const float*)d_in[2];
    const float* W1 = (const float*)d_in[3];
    const float* b1 = (const float*)d_in[4];
    const float* E  = (const float*)d_in[5];
    const float* bn2_gamma = (const float*)d_in[6];
    const float* bn2_beta  = (const float*)d_in[7];
    const float* W2 = (const float*)d_in[8];
    const float* b2 = (const float*)d_in[9];

    float* ws = (float*)d_ws;
    float* Mp  = ws + OFF_MP;
    float* cp  = ws + OFF_CP;
    float* Q   = ws + OFF_Q;
    float* W2T = ws + OFF_W2T;
    float* u   = ws + OFF_U;
    float* cQ  = ws + OFF_CQ;
    float* pval = ws + OFF_PV;
    int* pidx   = (int*)(ws + OFF_PI);
    unsigned short* Ah = (unsigned short*)(ws + OFF_AH);
    unsigned short* Bh = (unsigned short*)(ws + OFF_BH);
    float* out = (float*)d_out;

    hipLaunchKernelGGL(prep1_kernel, dim3(768), dim3(256), 0, stream,
                       W1, W2, bn1_beta, bn2_gamma, bn2_beta, b2, W2T, u, cQ, out);
    hipLaunchKernelGGL(prep2_kernel, dim3(256), dim3(256), 0, stream,
                       E, W1, W2T, bn1_gamma, cQ, Mp, Q);
    hipLaunchKernelGGL(prep3_kernel, dim3(512), dim3(256), 0, stream, E, b1, u, cp);
    hipLaunchKernelGGL(pack_kernel, dim3(TOK / 32), dim3(256), 0, stream, inputs, Ah, NTA);
    hipLaunchKernelGGL(pack_kernel, dim3(KCB / 32), dim3(256), 0, stream, Mp, Bh, NTB);
    hipLaunchKernelGGL(score_mfma_kernel, dim3(8192), dim3(256), 0, stream,
                       Ah, Bh, cp, pval, pidx);
    hipLaunchKernelGGL(gather_out_kernel, dim3(256), dim3(256), 0, stream,
                       inputs, Q, pval, pidx, out);
}

// Round 7
// 428.945 us; speedup vs baseline: 1.1849x; 1.1849x over previous
//
#include <hip/hip_runtime.h>
#include <math.h>
#include <stdint.h>

#define TOK 65536
#define DIN 256
#define EDIM 512
#define KCB 2048
#define NTA 4096        // A m-tiles (65536/16)
#define NTB 128         // B n-tiles (2048/16)

// workspace layout (float offsets), 64-float aligned
#define OFF_MP   0u                     // M' fp32 [2048*256]
#define OFF_CP   524288u                // c' [2048]
#define OFF_Q    526336u                // Q [2048*256]
#define OFF_W2T  1050624u               // W2T [512*256]
#define OFF_U    1181696u               // u [512]
#define OFF_CQ   1182208u               // cQ [256]
#define OFF_IDX  1182464u               // idx [65536] ints
#define OFF_AH   1248000u               // A packed bf16 [8][4096][512]
#define OFF_BH   5442304u               // B packed bf16 [8][128][512]
#define TOT_F    5704448u

typedef short short8 __attribute__((ext_vector_type(8)));
typedef float f32x4 __attribute__((ext_vector_type(4)));

__device__ __forceinline__ unsigned short bf16rne(float x) {
    uint32_t u = __float_as_uint(x);
    u += 0x7fffu + ((u >> 16) & 1u);
    return (unsigned short)(u >> 16);
}
__device__ __forceinline__ void async_load16(const void* g, void* l) {
    __builtin_amdgcn_global_load_lds((const __attribute__((address_space(1))) void*)g,
                                     (__attribute__((address_space(3))) void*)l, 16, 0, 0);
}

// fused: zero loss scalar + usage bins, then prep1 work.
// blocks 0..511: e -> W2T[e][o], u[e];  512..767: o -> cQ[o]
__global__ void prep1_kernel(const float* __restrict__ W1, const float* __restrict__ W2,
                             const float* __restrict__ bn1_beta, const float* __restrict__ bn2_gamma,
                             const float* __restrict__ bn2_beta, const float* __restrict__ b2,
                             float* __restrict__ W2T, float* __restrict__ u, float* __restrict__ cQ,
                             float* __restrict__ out) {
    __shared__ float red[256];
    const int b = blockIdx.x, t = threadIdx.x;
    const int gid = b * 256 + t;
    if (gid == 0) out[0] = 0.0f;
    if (gid < KCB) out[1 + TOK * DIN + gid] = 0.0f;
    const float s = 1.0f / sqrtf(1.0f + 1e-5f);
    if (b < EDIM) {
        int e = b;
        W2T[e * DIN + t] = bn2_gamma[e] * s * W2[t * EDIM + e];
        float v = bn1_beta[t] * W1[e * DIN + t];
        red[t] = v; __syncthreads();
        for (int off = 128; off; off >>= 1) { if (t < off) red[t] += red[t + off]; __syncthreads(); }
        if (t == 0) u[e] = red[0];
    } else {
        int o = b - EDIM;
        float v = bn2_beta[t] * W2[o * EDIM + t] + bn2_beta[t + 256] * W2[o * EDIM + t + 256];
        red[t] = v; __syncthreads();
        for (int off = 128; off; off >>= 1) { if (t < off) red[t] += red[t + off]; __syncthreads(); }
        if (t == 0) cQ[o] = b2[o] + red[0];
    }
}

// per block: 8 codebook rows, E-tile in LDS, W streamed from L2 once per block.
__global__ __launch_bounds__(256) void prep2_kernel(const float* __restrict__ E, const float* __restrict__ W1,
                                                    const float* __restrict__ W2T, const float* __restrict__ bn1_gamma,
                                                    const float* __restrict__ cQ,
                                                    float* __restrict__ Mp, float* __restrict__ Q) {
    __shared__ float Elds[8 * EDIM]; // [r][e] 16 KB
    const int k0 = blockIdx.x * 8, t = threadIdx.x;
    const float4* src = (const float4*)(E + (size_t)k0 * EDIM);
    float4* dst = (float4*)Elds;
#pragma unroll
    for (int i = 0; i < 4; i++) dst[i * 256 + t] = src[i * 256 + t];
    __syncthreads();
    float m[8] = {0, 0, 0, 0, 0, 0, 0, 0};
    float q[8] = {0, 0, 0, 0, 0, 0, 0, 0};
    for (int e = 0; e < EDIM; e++) {
        float w1 = W1[e * DIN + t];
        float w2 = W2T[e * DIN + t];
#pragma unroll
        for (int r = 0; r < 8; r++) {
            float ev = Elds[r * EDIM + e];   // same-address broadcast, conflict-free
            m[r] += ev * w1; q[r] += ev * w2;
        }
    }
    const float s = 1.0f / sqrtf(1.0f + 1e-5f);
    const float gs = bn1_gamma[t] * s;
    const float cq = cQ[t];
#pragma unroll
    for (int r = 0; r < 8; r++) {
        Mp[(size_t)(k0 + r) * DIN + t] = gs * m[r];
        Q[(size_t)(k0 + r) * DIN + t] = q[r] + cq;
    }
}

// fused: prep3 (c'[k], one wave per row, all 512 blocks) + packB (blocks 0..63).
__global__ __launch_bounds__(256) void prep3_packB_kernel(const float* __restrict__ E, const float* __restrict__ b1,
                                                          const float* __restrict__ u, float* __restrict__ cp,
                                                          const float* __restrict__ Mp,
                                                          unsigned short* __restrict__ Bh) {
    __shared__ __align__(16) unsigned short Hs[32 * 264];
    const int t = threadIdx.x, lane = t & 63;
    {   // prep3: c'[k] = sum_e E[k][e]*(b1[e]+u[e]) - 0.5*sum_e E[k][e]^2
        const int k = blockIdx.x * 4 + (t >> 6);
        const float4* er = (const float4*)(E + (size_t)k * EDIM);
        float sa = 0.0f, sb = 0.0f;
#pragma unroll
        for (int i = 0; i < 2; i++) {
            int j4 = lane * 2 + i;
            float4 ev = er[j4];
            int e = j4 * 4;
            sa += ev.x * (b1[e] + u[e]) + ev.y * (b1[e + 1] + u[e + 1])
                + ev.z * (b1[e + 2] + u[e + 2]) + ev.w * (b1[e + 3] + u[e + 3]);
            sb += ev.x * ev.x + ev.y * ev.y + ev.z * ev.z + ev.w * ev.w;
        }
        float v = sa - 0.5f * sb;
#pragma unroll
        for (int off = 32; off; off >>= 1) v += __shfl_down(v, off, 64);
        if (lane == 0) cp[k] = v;
    }
    if (blockIdx.x >= 64) return;    // uniform per-block branch
    // packB: Mp rows [b*32, b*32+32) -> fragment-tile order
    const int r0 = blockIdx.x * 32;
    const float4* src = (const float4*)(Mp + (size_t)r0 * DIN);
#pragma unroll
    for (int i = 0; i < 8; i++) {
        int id = i * 256 + t;
        int row = id >> 6, c4 = id & 63;
        float4 v = src[id];
        float f[4] = {v.x, v.y, v.z, v.w};
        ushort4 H;
        unsigned short* hp = (unsigned short*)&H;
#pragma unroll
        for (int j = 0; j < 4; j++) hp[j] = bf16rne(f[j]);
        *(ushort4*)&Hs[row * 264 + c4 * 4] = H;
    }
    __syncthreads();
    const int w = t >> 6;
#pragma unroll
    for (int q = 0; q < 4; q++) {
        int fb = q * 4 + w;              // 0..15
        int tl = fb >> 3, kc = fb & 7;
        int srow = tl * 16 + (lane & 15);
        int scol = kc * 32 + (lane >> 4) * 8;
        short8 vh = *(const short8*)&Hs[srow * 264 + scol];
        size_t off = ((size_t)kc * NTB + (r0 >> 4) + tl) * 512 + lane * 8;
        *(short8*)&Bh[off] = vh;
    }
}

// X[R x 256] fp32 -> bf16 in MFMA fragment-tile order (A).
__global__ __launch_bounds__(256) void packA_kernel(const float* __restrict__ X,
                                                    unsigned short* __restrict__ Hp) {
    __shared__ __align__(16) unsigned short Hs[32 * 264];
    const int t = threadIdx.x;
    const int r0 = blockIdx.x * 32;
    const float4* src = (const float4*)(X + (size_t)r0 * DIN);
#pragma unroll
    for (int i = 0; i < 8; i++) {
        int id = i * 256 + t;
        int row = id >> 6, c4 = id & 63;
        float4 v = src[id];
        float f[4] = {v.x, v.y, v.z, v.w};
        ushort4 H;
        unsigned short* hp = (unsigned short*)&H;
#pragma unroll
        for (int j = 0; j < 4; j++) hp[j] = bf16rne(f[j]);
        *(ushort4*)&Hs[row * 264 + c4 * 4] = H;
    }
    __syncthreads();
    const int lane = t & 63, w = t >> 6;
#pragma unroll
    for (int q = 0; q < 4; q++) {
        int fb = q * 4 + w;
        int tl = fb >> 3, kc = fb & 7;
        int srow = tl * 16 + (lane & 15);
        int scol = kc * 32 + (lane >> 4) * 8;
        short8 vh = *(const short8*)&Hs[srow * 264 + scol];
        size_t off = ((size_t)kc * NTA + (r0 >> 4) + tl) * 512 + lane * 8;
        *(short8*)&Hp[off] = vh;
    }
}

// A-stationary scorer: block = 256 rows x ALL 2048 codes. 4 waves x 64 rows.
// A fragments live in registers (af[8][4], loaded once). B chunk (64 cols,
// full K = 32 KB) double-buffered in LDS, broadcast to all waves. 32 stages,
// one barrier each; staging issued a full stage ahead -> barrier drain is free.
// Argmax entirely in-register; final cross-lane reduce; writes idx directly.
__global__ __launch_bounds__(256) void score_mfma_kernel(const unsigned short* __restrict__ Ah,
                                                         const unsigned short* __restrict__ Bh,
                                                         const float* __restrict__ cp,
                                                         int* __restrict__ idxOut) {
    __shared__ __align__(16) unsigned short Blds[2][32 * 512];  // 64 KB
    const int t = threadIdx.x, lane = t & 63, w = t >> 6;
    const int m0 = blockIdx.x * 256;
    const int mt0 = (m0 >> 4) + w * 4;
    const int fr = lane & 15;
    const short8* A8 = (const short8*)Ah;

    // A slice in registers: 128 VGPR, loaded once, zero re-reads
    short8 af[8][4];
#pragma unroll
    for (int kc = 0; kc < 8; kc++)
#pragma unroll
        for (int mt = 0; mt < 4; mt++)
            af[kc][mt] = A8[((size_t)kc * NTA + mt0 + mt) * 64 + lane];

    // stage 0 prologue: wave w stages slots [8w, 8w+8) of (kc,nt) pairs
#pragma unroll
    for (int i = 0; i < 8; i++) {
        int slot = w * 8 + i;
        int kc = slot >> 2, nt = slot & 3;
        async_load16(Bh + ((size_t)kc * NTB + nt) * 512 + lane * 8,
                     &Blds[0][slot * 512 + lane * 8]);
    }
    __syncthreads();

    float bestv[4][4];
    int besti[4][4];
#pragma unroll
    for (int mt = 0; mt < 4; mt++)
#pragma unroll
        for (int r = 0; r < 4; r++) { bestv[mt][r] = -3.4e38f; besti[mt][r] = 0; }

#pragma unroll 1
    for (int s = 0; s < 32; s++) {
        const int cur = s & 1;
        if (s < 31) {
            const int nxt = cur ^ 1;
#pragma unroll
            for (int i = 0; i < 8; i++) {
                int slot = w * 8 + i;
                int kc = slot >> 2, nt = slot & 3;
                async_load16(Bh + ((size_t)kc * NTB + (s + 1) * 4 + nt) * 512 + lane * 8,
                             &Blds[nxt][slot * 512 + lane * 8]);
            }
        }
        f32x4 acc[4][4];
#pragma unroll
        for (int mt = 0; mt < 4; mt++)
#pragma unroll
            for (int nt = 0; nt < 4; nt++) acc[mt][nt] = (f32x4){0.f, 0.f, 0.f, 0.f};
#pragma unroll
        for (int kc = 0; kc < 8; kc++) {
            short8 bf[4];
#pragma unroll
            for (int nt = 0; nt < 4; nt++)
                bf[nt] = *(const short8*)&Blds[cur][(kc * 4 + nt) * 512 + lane * 8];
#pragma unroll
            for (int mt = 0; mt < 4; mt++)
#pragma unroll
                for (int nt = 0; nt < 4; nt++)
                    acc[mt][nt] = __builtin_amdgcn_mfma_f32_16x16x32_bf16(af[kc][mt], bf[nt], acc[mt][nt], 0, 0, 0);
        }
        // chunk argmax: cols s*64 + nt*16 + fr
        float cpv[4];
#pragma unroll
        for (int nt = 0; nt < 4; nt++) cpv[nt] = cp[s * 64 + nt * 16 + fr];
#pragma unroll
        for (int mt = 0; mt < 4; mt++)
#pragma unroll
            for (int r = 0; r < 4; r++) {
                float bv = acc[mt][0][r] + cpv[0];
                int bc = s * 64 + fr;
#pragma unroll
                for (int nt = 1; nt < 4; nt++) {
                    float v = acc[mt][nt][r] + cpv[nt];
                    if (v > bv) { bv = v; bc = s * 64 + nt * 16 + fr; }  // asc nt: ties -> lower
                }
                if (bv > bestv[mt][r]) { bestv[mt][r] = bv; besti[mt][r] = bc; }  // asc s: ties -> lower
            }
        __syncthreads();
    }
    // cross-fr (16 lanes) argmax reduce, tie -> lower idx; write final idx
#pragma unroll
    for (int mt = 0; mt < 4; mt++)
#pragma unroll
        for (int r = 0; r < 4; r++) {
            float bv = bestv[mt][r];
            int bc = besti[mt][r];
#pragma unroll
            for (int xm = 1; xm < 16; xm <<= 1) {
                float ov = __shfl_xor(bv, xm, 64);
                int oc = __shfl_xor(bc, xm, 64);
                if (ov > bv || (ov == bv && oc < bc)) { bv = ov; bc = oc; }
            }
            if (fr == 0) {
                int row = m0 + w * 64 + mt * 16 + (lane >> 4) * 4 + r;
                idxOut[row] = bc;
            }
        }
}

// gather: k = idx[row]; Q[k] -> out, fused loss + usage histogram. 32 rows/wave.
__global__ __launch_bounds__(256) void gather_out_kernel(const float* __restrict__ flat,
                                                         const float* __restrict__ Q,
                                                         const int* __restrict__ idx,
                                                         float* __restrict__ out) {
    const int t = threadIdx.x;
    const int lane = t & 63;
    const int gw = blockIdx.x * 4 + (t >> 6);
    float lsum = 0.0f;
    for (int r = 0; r < 32; r++) {
        int row = gw * 32 + r;
        int k = idx[row];                       // same-address broadcast
        const float* qr = Q + (size_t)k * DIN;
        const float* xr = flat + (size_t)row * DIN;
        float* ob = out + 1 + (size_t)row * DIN;
#pragma unroll
        for (int cc = 0; cc < 4; cc++) {
            int j = lane + 64 * cc;
            float q = qr[j];
            float d = q - xr[j];
            lsum += d * d;
            ob[j] = q;
        }
        if (lane == 0) atomicAdd(out + 1 + TOK * DIN + k, 1.0f / (float)TOK);
    }
#pragma unroll
    for (int off = 32; off; off >>= 1) lsum += __shfl_down(lsum, off, 64);
    if (lane == 0) atomicAdd(out, lsum * (1.25f / (float)((size_t)TOK * DIN)));
}

extern "C" void kernel_launch(void* const* d_in, const int* in_sizes, int n_in,
                              void* d_out, int out_size, void* d_ws, size_t ws_size,
                              hipStream_t stream) {
    const float* inputs = (const float*)d_in[0];
    const float* bn1_gamma = (const float*)d_in[1];
    const float* bn1_beta  = (const float*)d_in[2];
    const float* W1 = (const float*)d_in[3];
    const float* b1 = (const float*)d_in[4];
    const float* E  = (const float*)d_in[5];
    const float* bn2_gamma = (const float*)d_in[6];
    const float* bn2_beta  = (const float*)d_in[7];
    const float* W2 = (const float*)d_in[8];
    const float* b2 = (const float*)d_in[9];

    float* ws = (float*)d_ws;
    float* Mp  = ws + OFF_MP;
    float* cp  = ws + OFF_CP;
    float* Q   = ws + OFF_Q;
    float* W2T = ws + OFF_W2T;
    float* u   = ws + OFF_U;
    float* cQ  = ws + OFF_CQ;
    int* idx   = (int*)(ws + OFF_IDX);
    unsigned short* Ah = (unsigned short*)(ws + OFF_AH);
    unsigned short* Bh = (unsigned short*)(ws + OFF_BH);
    float* out = (float*)d_out;

    hipLaunchKernelGGL(packA_kernel, dim3(TOK / 32), dim3(256), 0, stream, inputs, Ah);
    hipLaunchKernelGGL(prep1_kernel, dim3(768), dim3(256), 0, stream,
                       W1, W2, bn1_beta, bn2_gamma, bn2_beta, b2, W2T, u, cQ, out);
    hipLaunchKernelGGL(prep2_kernel, dim3(256), dim3(256), 0, stream,
                       E, W1, W2T, bn1_gamma, cQ, Mp, Q);
    hipLaunchKernelGGL(prep3_packB_kernel, dim3(512), dim3(256), 0, stream,
                       E, b1, u, cp, Mp, Bh);
    hipLaunchKernelGGL(score_mfma_kernel, dim3(256), dim3(256), 0, stream,
                       Ah, Bh, cp, idx);
    hipLaunchKernelGGL(gather_out_kernel, dim3(512), dim3(256), 0, stream,
                       inputs, Q, idx, out);
}

// Round 8
// 320.135 us; speedup vs baseline: 1.5877x; 1.3399x over previous
//
#include <hip/hip_runtime.h>
#include <math.h>
#include <stdint.h>

#define TOK 65536
#define DIN 256
#define EDIM 512
#define KCB 2048
#define NTA 4096        // A m-tiles (65536/16)
#define NTB 128         // B n-tiles (2048/16)

// workspace layout (float offsets), 64-float aligned
#define OFF_MP   0u                     // M' fp32 [2048*256]
#define OFF_CP   524288u                // c' [2048]
#define OFF_Q    526336u                // Q [2048*256]
#define OFF_W2T  1050624u               // W2T [512*256]
#define OFF_U    1181696u               // u [512]
#define OFF_CQ   1182208u               // cQ [256]
#define OFF_IDX  1182464u               // idx [65536] ints
#define OFF_AH   1248000u               // A packed bf16 [8][4096][512]
#define OFF_BH   5442304u               // B packed bf16 [8][128][512]
#define TOT_F    5704448u

typedef short short8 __attribute__((ext_vector_type(8)));
typedef float f32x4 __attribute__((ext_vector_type(4)));

__device__ __forceinline__ unsigned short bf16rne(float x) {
    uint32_t u = __float_as_uint(x);
    u += 0x7fffu + ((u >> 16) & 1u);
    return (unsigned short)(u >> 16);
}
__device__ __forceinline__ void async_load16(const void* g, void* l) {
    __builtin_amdgcn_global_load_lds((const __attribute__((address_space(1))) void*)g,
                                     (__attribute__((address_space(3))) void*)l, 16, 0, 0);
}

// fused: zero loss scalar + usage bins, then prep1 work.
// blocks 0..511: e -> W2T[e][o], u[e];  512..767: o -> cQ[o]
__global__ void prep1_kernel(const float* __restrict__ W1, const float* __restrict__ W2,
                             const float* __restrict__ bn1_beta, const float* __restrict__ bn2_gamma,
                             const float* __restrict__ bn2_beta, const float* __restrict__ b2,
                             float* __restrict__ W2T, float* __restrict__ u, float* __restrict__ cQ,
                             float* __restrict__ out) {
    __shared__ float red[256];
    const int b = blockIdx.x, t = threadIdx.x;
    const int gid = b * 256 + t;
    if (gid == 0) out[0] = 0.0f;
    if (gid < KCB) out[1 + TOK * DIN + gid] = 0.0f;
    const float s = 1.0f / sqrtf(1.0f + 1e-5f);
    if (b < EDIM) {
        int e = b;
        W2T[e * DIN + t] = bn2_gamma[e] * s * W2[t * EDIM + e];
        float v = bn1_beta[t] * W1[e * DIN + t];
        red[t] = v; __syncthreads();
        for (int off = 128; off; off >>= 1) { if (t < off) red[t] += red[t + off]; __syncthreads(); }
        if (t == 0) u[e] = red[0];
    } else {
        int o = b - EDIM;
        float v = bn2_beta[t] * W2[o * EDIM + t] + bn2_beta[t + 256] * W2[o * EDIM + t + 256];
        red[t] = v; __syncthreads();
        for (int off = 128; off; off >>= 1) { if (t < off) red[t] += red[t + off]; __syncthreads(); }
        if (t == 0) cQ[o] = b2[o] + red[0];
    }
}

// per block: 4 codebook rows; e-loop unrolled x8 -> 16 independent loads in
// flight per thread; 512 blocks = 2 blocks/CU for wave-level latency hiding.
__global__ __launch_bounds__(256) void prep2_kernel(const float* __restrict__ E, const float* __restrict__ W1,
                                                    const float* __restrict__ W2T, const float* __restrict__ bn1_gamma,
                                                    const float* __restrict__ cQ,
                                                    float* __restrict__ Mp, float* __restrict__ Q) {
    __shared__ float Elds[4 * EDIM]; // [r][e] 8 KB
    const int k0 = blockIdx.x * 4, t = threadIdx.x;
    const float4* src = (const float4*)(E + (size_t)k0 * EDIM);
    float4* dst = (float4*)Elds;
    dst[t] = src[t];
    dst[256 + t] = src[256 + t];
    __syncthreads();
    float m[4] = {0, 0, 0, 0};
    float q[4] = {0, 0, 0, 0};
    for (int e0 = 0; e0 < EDIM; e0 += 8) {
        float w1v[8], w2v[8];
#pragma unroll
        for (int j = 0; j < 8; j++) {
            w1v[j] = W1[(e0 + j) * DIN + t];
            w2v[j] = W2T[(e0 + j) * DIN + t];
        }
#pragma unroll
        for (int j = 0; j < 8; j++) {
#pragma unroll
            for (int r = 0; r < 4; r++) {
                float ev = Elds[r * EDIM + e0 + j];   // same-address broadcast
                m[r] += ev * w1v[j]; q[r] += ev * w2v[j];
            }
        }
    }
    const float s = 1.0f / sqrtf(1.0f + 1e-5f);
    const float gs = bn1_gamma[t] * s;
    const float cq = cQ[t];
#pragma unroll
    for (int r = 0; r < 4; r++) {
        Mp[(size_t)(k0 + r) * DIN + t] = gs * m[r];
        Q[(size_t)(k0 + r) * DIN + t] = q[r] + cq;
    }
}

// fused: prep3 (c'[k], one wave per row, all 512 blocks) + packB (blocks 0..63).
__global__ __launch_bounds__(256) void prep3_packB_kernel(const float* __restrict__ E, const float* __restrict__ b1,
                                                          const float* __restrict__ u, float* __restrict__ cp,
                                                          const float* __restrict__ Mp,
                                                          unsigned short* __restrict__ Bh) {
    __shared__ __align__(16) unsigned short Hs[32 * 264];
    const int t = threadIdx.x, lane = t & 63;
    {   // prep3: c'[k] = sum_e E[k][e]*(b1[e]+u[e]) - 0.5*sum_e E[k][e]^2
        const int k = blockIdx.x * 4 + (t >> 6);
        const float4* er = (const float4*)(E + (size_t)k * EDIM);
        float sa = 0.0f, sb = 0.0f;
#pragma unroll
        for (int i = 0; i < 2; i++) {
            int j4 = lane * 2 + i;
            float4 ev = er[j4];
            int e = j4 * 4;
            sa += ev.x * (b1[e] + u[e]) + ev.y * (b1[e + 1] + u[e + 1])
                + ev.z * (b1[e + 2] + u[e + 2]) + ev.w * (b1[e + 3] + u[e + 3]);
            sb += ev.x * ev.x + ev.y * ev.y + ev.z * ev.z + ev.w * ev.w;
        }
        float v = sa - 0.5f * sb;
#pragma unroll
        for (int off = 32; off; off >>= 1) v += __shfl_down(v, off, 64);
        if (lane == 0) cp[k] = v;
    }
    if (blockIdx.x >= 64) return;    // uniform per-block branch
    const int r0 = blockIdx.x * 32;
    const float4* src = (const float4*)(Mp + (size_t)r0 * DIN);
#pragma unroll
    for (int i = 0; i < 8; i++) {
        int id = i * 256 + t;
        int row = id >> 6, c4 = id & 63;
        float4 v = src[id];
        float f[4] = {v.x, v.y, v.z, v.w};
        ushort4 H;
        unsigned short* hp = (unsigned short*)&H;
#pragma unroll
        for (int j = 0; j < 4; j++) hp[j] = bf16rne(f[j]);
        *(ushort4*)&Hs[row * 264 + c4 * 4] = H;
    }
    __syncthreads();
    const int w = t >> 6;
#pragma unroll
    for (int q = 0; q < 4; q++) {
        int fb = q * 4 + w;
        int tl = fb >> 3, kc = fb & 7;
        int srow = tl * 16 + (lane & 15);
        int scol = kc * 32 + (lane >> 4) * 8;
        short8 vh = *(const short8*)&Hs[srow * 264 + scol];
        size_t off = ((size_t)kc * NTB + (r0 >> 4) + tl) * 512 + lane * 8;
        *(short8*)&Bh[off] = vh;
    }
}

// X[R x 256] fp32 -> bf16 in MFMA fragment-tile order (A).
__global__ __launch_bounds__(256) void packA_kernel(const float* __restrict__ X,
                                                    unsigned short* __restrict__ Hp) {
    __shared__ __align__(16) unsigned short Hs[32 * 264];
    const int t = threadIdx.x;
    const int r0 = blockIdx.x * 32;
    const float4* src = (const float4*)(X + (size_t)r0 * DIN);
#pragma unroll
    for (int i = 0; i < 8; i++) {
        int id = i * 256 + t;
        int row = id >> 6, c4 = id & 63;
        float4 v = src[id];
        float f[4] = {v.x, v.y, v.z, v.w};
        ushort4 H;
        unsigned short* hp = (unsigned short*)&H;
#pragma unroll
        for (int j = 0; j < 4; j++) hp[j] = bf16rne(f[j]);
        *(ushort4*)&Hs[row * 264 + c4 * 4] = H;
    }
    __syncthreads();
    const int lane = t & 63, w = t >> 6;
#pragma unroll
    for (int q = 0; q < 4; q++) {
        int fb = q * 4 + w;
        int tl = fb >> 3, kc = fb & 7;
        int srow = tl * 16 + (lane & 15);
        int scol = kc * 32 + (lane >> 4) * 8;
        short8 vh = *(const short8*)&Hs[srow * 264 + scol];
        size_t off = ((size_t)kc * NTA + (r0 >> 4) + tl) * 512 + lane * 8;
        *(short8*)&Hp[off] = vh;
    }
}

// A-stationary scorer v2: block = 128 rows x ALL 2048 codes, 32 KB LDS ->
// 2 blocks/CU (2 waves/SIMD latency hiding). A in registers (af[8][2]).
// B chunk = 32 cols full-K (16 KB) double-buffered; 64 stages, 1 barrier each.
// Argmax in-register; writes final idx.
__global__ __launch_bounds__(256) void score_mfma_kernel(const unsigned short* __restrict__ Ah,
                                                         const unsigned short* __restrict__ Bh,
                                                         const float* __restrict__ cp,
                                                         int* __restrict__ idxOut) {
    __shared__ __align__(16) unsigned short Blds[2][16 * 512];  // 2 x 16 KB
    const int t = threadIdx.x, lane = t & 63, w = t >> 6;
    const int m0 = blockIdx.x * 128;
    const int mt0 = (m0 >> 4) + w * 2;
    const int fr = lane & 15;
    const short8* A8 = (const short8*)Ah;

    // A slice in registers: 64 VGPR, loaded once
    short8 af[8][2];
#pragma unroll
    for (int kc = 0; kc < 8; kc++)
#pragma unroll
        for (int mt = 0; mt < 2; mt++)
            af[kc][mt] = A8[((size_t)kc * NTA + mt0 + mt) * 64 + lane];

    // prefetch chunk 0: 16 tiles (kc*2+nt); thread (i,w) stages tile i*4+w
#pragma unroll
    for (int i = 0; i < 4; i++) {
        int tl = i * 4 + w;
        int kc = tl >> 1, nt = tl & 1;
        async_load16(Bh + ((size_t)kc * NTB + nt) * 512 + lane * 8,
                     &Blds[0][tl * 512 + lane * 8]);
    }
    __syncthreads();

    float bestv[2][4];
    int besti[2][4];
#pragma unroll
    for (int mt = 0; mt < 2; mt++)
#pragma unroll
        for (int r = 0; r < 4; r++) { bestv[mt][r] = -3.4e38f; besti[mt][r] = 0; }

#pragma unroll 1
    for (int s = 0; s < 64; s++) {
        const int cur = s & 1;
        if (s < 63) {
            const int nxt = cur ^ 1;
#pragma unroll
            for (int i = 0; i < 4; i++) {
                int tl = i * 4 + w;
                int kc = tl >> 1, nt = tl & 1;
                async_load16(Bh + ((size_t)kc * NTB + (s + 1) * 2 + nt) * 512 + lane * 8,
                             &Blds[nxt][tl * 512 + lane * 8]);
            }
        }
        f32x4 acc[2][2];
#pragma unroll
        for (int mt = 0; mt < 2; mt++)
#pragma unroll
            for (int nt = 0; nt < 2; nt++) acc[mt][nt] = (f32x4){0.f, 0.f, 0.f, 0.f};
#pragma unroll
        for (int kc = 0; kc < 8; kc++) {
            short8 bf0 = *(const short8*)&Blds[cur][(kc * 2 + 0) * 512 + lane * 8];
            short8 bf1 = *(const short8*)&Blds[cur][(kc * 2 + 1) * 512 + lane * 8];
            acc[0][0] = __builtin_amdgcn_mfma_f32_16x16x32_bf16(af[kc][0], bf0, acc[0][0], 0, 0, 0);
            acc[0][1] = __builtin_amdgcn_mfma_f32_16x16x32_bf16(af[kc][0], bf1, acc[0][1], 0, 0, 0);
            acc[1][0] = __builtin_amdgcn_mfma_f32_16x16x32_bf16(af[kc][1], bf0, acc[1][0], 0, 0, 0);
            acc[1][1] = __builtin_amdgcn_mfma_f32_16x16x32_bf16(af[kc][1], bf1, acc[1][1], 0, 0, 0);
        }
        float cpv0 = cp[s * 32 + fr];
        float cpv1 = cp[s * 32 + 16 + fr];
#pragma unroll
        for (int mt = 0; mt < 2; mt++)
#pragma unroll
            for (int r = 0; r < 4; r++) {
                float bv = acc[mt][0][r] + cpv0;
                int bc = s * 32 + fr;
                float v1 = acc[mt][1][r] + cpv1;
                if (v1 > bv) { bv = v1; bc = s * 32 + 16 + fr; }   // asc nt: ties -> lower
                if (bv > bestv[mt][r]) { bestv[mt][r] = bv; besti[mt][r] = bc; }  // asc s
            }
        __syncthreads();
    }
    // cross-fr (16 lanes) argmax reduce, tie -> lower idx; write final idx
#pragma unroll
    for (int mt = 0; mt < 2; mt++)
#pragma unroll
        for (int r = 0; r < 4; r++) {
            float bv = bestv[mt][r];
            int bc = besti[mt][r];
#pragma unroll
            for (int xm = 1; xm < 16; xm <<= 1) {
                float ov = __shfl_xor(bv, xm, 64);
                int oc = __shfl_xor(bc, xm, 64);
                if (ov > bv || (ov == bv && oc < bc)) { bv = ov; bc = oc; }
            }
            if (fr == 0) {
                int row = m0 + (w * 2 + mt) * 16 + (lane >> 4) * 4 + r;
                idxOut[row] = bc;
            }
        }
}

// gather: k = idx[row]; Q[k] -> out, fused loss + usage histogram. 16 rows/wave.
__global__ __launch_bounds__(256) void gather_out_kernel(const float* __restrict__ flat,
                                                         const float* __restrict__ Q,
                                                         const int* __restrict__ idx,
                                                         float* __restrict__ out) {
    const int t = threadIdx.x;
    const int lane = t & 63;
    const int gw = blockIdx.x * 4 + (t >> 6);   // 4096 waves
    float lsum = 0.0f;
    for (int r = 0; r < 16; r++) {
        int row = gw * 16 + r;
        int k = idx[row];                       // same-address broadcast
        const float* qr = Q + (size_t)k * DIN;
        const float* xr = flat + (size_t)row * DIN;
        float* ob = out + 1 + (size_t)row * DIN;
#pragma unroll
        for (int cc = 0; cc < 4; cc++) {
            int j = lane + 64 * cc;
            float q = qr[j];
            float d = q - xr[j];
            lsum += d * d;
            ob[j] = q;
        }
        if (lane == 0) atomicAdd(out + 1 + TOK * DIN + k, 1.0f / (float)TOK);
    }
#pragma unroll
    for (int off = 32; off; off >>= 1) lsum += __shfl_down(lsum, off, 64);
    if (lane == 0) atomicAdd(out, lsum * (1.25f / (float)((size_t)TOK * DIN)));
}

extern "C" void kernel_launch(void* const* d_in, const int* in_sizes, int n_in,
                              void* d_out, int out_size, void* d_ws, size_t ws_size,
                              hipStream_t stream) {
    const float* inputs = (const float*)d_in[0];
    const float* bn1_gamma = (const float*)d_in[1];
    const float* bn1_beta  = (const float*)d_in[2];
    const float* W1 = (const float*)d_in[3];
    const float* b1 = (const float*)d_in[4];
    const float* E  = (const float*)d_in[5];
    const float* bn2_gamma = (const float*)d_in[6];
    const float* bn2_beta  = (const float*)d_in[7];
    const float* W2 = (const float*)d_in[8];
    const float* b2 = (const float*)d_in[9];

    float* ws = (float*)d_ws;
    float* Mp  = ws + OFF_MP;
    float* cp  = ws + OFF_CP;
    float* Q   = ws + OFF_Q;
    float* W2T = ws + OFF_W2T;
    float* u   = ws + OFF_U;
    float* cQ  = ws + OFF_CQ;
    int* idx   = (int*)(ws + OFF_IDX);
    unsigned short* Ah = (unsigned short*)(ws + OFF_AH);
    unsigned short* Bh = (unsigned short*)(ws + OFF_BH);
    float* out = (float*)d_out;

    hipLaunchKernelGGL(packA_kernel, dim3(TOK / 32), dim3(256), 0, stream, inputs, Ah);
    hipLaunchKernelGGL(prep1_kernel, dim3(768), dim3(256), 0, stream,
                       W1, W2, bn1_beta, bn2_gamma, bn2_beta, b2, W2T, u, cQ, out);
    hipLaunchKernelGGL(prep2_kernel, dim3(512), dim3(256), 0, stream,
                       E, W1, W2T, bn1_gamma, cQ, Mp, Q);
    hipLaunchKernelGGL(prep3_packB_kernel, dim3(512), dim3(256), 0, stream,
                       E, b1, u, cp, Mp, Bh);
    hipLaunchKernelGGL(score_mfma_kernel, dim3(512), dim3(256), 0, stream,
                       Ah, Bh, cp, idx);
    hipLaunchKernelGGL(gather_out_kernel, dim3(1024), dim3(256), 0, stream,
                       inputs, Q, idx, out);
}

// Round 9
// 278.505 us; speedup vs baseline: 1.8250x; 1.1495x over previous
//
#include <hip/hip_runtime.h>
#include <math.h>
#include <stdint.h>

#define TOK 65536
#define DIN 256
#define EDIM 512
#define KCB 2048
#define NTB 128         // B n-tiles (2048/16)

// workspace layout (float offsets), 64-float aligned
#define OFF_MP   0u                     // M' fp32 [2048*256]
#define OFF_CP   524288u                // c' [2048]
#define OFF_Q    526336u                // Q [2048*256]
#define OFF_W2T  1050624u               // W2T [512*256]
#define OFF_U    1181696u               // u [512]
#define OFF_CQ   1182208u               // cQ [256]
#define OFF_BH   1182464u               // B packed bf16 [8][128][512]
#define TOT_F    1444608u

typedef short short8 __attribute__((ext_vector_type(8)));
typedef float f32x4 __attribute__((ext_vector_type(4)));

__device__ __forceinline__ unsigned short bf16rne(float x) {
    uint32_t u = __float_as_uint(x);
    u += 0x7fffu + ((u >> 16) & 1u);
    return (unsigned short)(u >> 16);
}
__device__ __forceinline__ void async_load16(const void* g, void* l) {
    __builtin_amdgcn_global_load_lds((const __attribute__((address_space(1))) void*)g,
                                     (__attribute__((address_space(3))) void*)l, 16, 0, 0);
}

// fused: zero loss scalar + usage bins, then W2T / u / cQ.
// blocks 0..511: e -> W2T[e][o], u[e];  512..767: o -> cQ[o]
__global__ void prep1_kernel(const float* __restrict__ W1, const float* __restrict__ W2,
                             const float* __restrict__ bn1_beta, const float* __restrict__ bn2_gamma,
                             const float* __restrict__ bn2_beta, const float* __restrict__ b2,
                             float* __restrict__ W2T, float* __restrict__ u, float* __restrict__ cQ,
                             float* __restrict__ out) {
    __shared__ float red[256];
    const int b = blockIdx.x, t = threadIdx.x;
    const int gid = b * 256 + t;
    if (gid == 0) out[0] = 0.0f;
    if (gid < KCB) out[1 + TOK * DIN + gid] = 0.0f;
    const float s = 1.0f / sqrtf(1.0f + 1e-5f);
    if (b < EDIM) {
        int e = b;
        W2T[e * DIN + t] = bn2_gamma[e] * s * W2[t * EDIM + e];
        float v = bn1_beta[t] * W1[e * DIN + t];
        red[t] = v; __syncthreads();
        for (int off = 128; off; off >>= 1) { if (t < off) red[t] += red[t + off]; __syncthreads(); }
        if (t == 0) u[e] = red[0];
    } else {
        int o = b - EDIM;
        float v = bn2_beta[t] * W2[o * EDIM + t] + bn2_beta[t + 256] * W2[o * EDIM + t + 256];
        red[t] = v; __syncthreads();
        for (int off = 128; off; off >>= 1) { if (t < off) red[t] += red[t + off]; __syncthreads(); }
        if (t == 0) cQ[o] = b2[o] + red[0];
    }
}

// per block: 4 codebook rows -> Mp, Q, AND c' (prep3 fused; E already in LDS).
__global__ __launch_bounds__(256) void prep2_kernel(const float* __restrict__ E, const float* __restrict__ W1,
                                                    const float* __restrict__ W2T, const float* __restrict__ bn1_gamma,
                                                    const float* __restrict__ cQ, const float* __restrict__ b1,
                                                    const float* __restrict__ u,
                                                    float* __restrict__ Mp, float* __restrict__ Q,
                                                    float* __restrict__ cp) {
    __shared__ float Elds[4 * EDIM]; // [r][e] row-major, 8 KB
    const int k0 = blockIdx.x * 4, t = threadIdx.x;
    const float4* src = (const float4*)(E + (size_t)k0 * EDIM);
    float4* dst = (float4*)Elds;
    dst[t] = src[t];
    dst[256 + t] = src[256 + t];
    __syncthreads();
    float m[4] = {0, 0, 0, 0};
    float q[4] = {0, 0, 0, 0};
    for (int e0 = 0; e0 < EDIM; e0 += 8) {
        float w1v[8], w2v[8];
#pragma unroll
        for (int j = 0; j < 8; j++) {
            w1v[j] = W1[(e0 + j) * DIN + t];
            w2v[j] = W2T[(e0 + j) * DIN + t];
        }
#pragma unroll
        for (int j = 0; j < 8; j++) {
#pragma unroll
            for (int r = 0; r < 4; r++) {
                float ev = Elds[r * EDIM + e0 + j];   // same-address broadcast
                m[r] += ev * w1v[j]; q[r] += ev * w2v[j];
            }
        }
    }
    const float s = 1.0f / sqrtf(1.0f + 1e-5f);
    const float gs = bn1_gamma[t] * s;
    const float cq = cQ[t];
#pragma unroll
    for (int r = 0; r < 4; r++) {
        Mp[(size_t)(k0 + r) * DIN + t] = gs * m[r];
        Q[(size_t)(k0 + r) * DIN + t] = q[r] + cq;
    }
    // fused prep3: c'[k0+r] = E[k]·(b1+u) - 0.5*||E[k]||², one wave per row
    const int r = t >> 6, l = t & 63;
    float sa = 0.0f, sb = 0.0f;
#pragma unroll
    for (int i = 0; i < 8; i++) {
        int e = l + i * 64;
        float ev = Elds[r * EDIM + e];
        float be = b1[e] + u[e];
        sa += ev * be; sb += ev * ev;
    }
    float v = sa - 0.5f * sb;
#pragma unroll
    for (int off = 32; off; off >>= 1) v += __shfl_down(v, off, 64);
    if (l == 0) cp[k0 + r] = v;
}

// Mp[2048 x 256] fp32 -> bf16 fragment-tile order (B). 64 blocks x 32 rows.
__global__ __launch_bounds__(256) void packB_kernel(const float* __restrict__ Mp,
                                                    unsigned short* __restrict__ Bh) {
    __shared__ __align__(16) unsigned short Hs[32 * 264];
    const int t = threadIdx.x, lane = t & 63, w = t >> 6;
    const int r0 = blockIdx.x * 32;
    const float4* src = (const float4*)(Mp + (size_t)r0 * DIN);
#pragma unroll
    for (int i = 0; i < 8; i++) {
        int id = i * 256 + t;
        int row = id >> 6, c4 = id & 63;
        float4 v = src[id];
        float f[4] = {v.x, v.y, v.z, v.w};
        ushort4 H;
        unsigned short* hp = (unsigned short*)&H;
#pragma unroll
        for (int j = 0; j < 4; j++) hp[j] = bf16rne(f[j]);
        *(ushort4*)&Hs[row * 264 + c4 * 4] = H;
    }
    __syncthreads();
#pragma unroll
    for (int q = 0; q < 4; q++) {
        int fb = q * 4 + w;
        int tl = fb >> 3, kc = fb & 7;
        int srow = tl * 16 + (lane & 15);
        int scol = kc * 32 + (lane >> 4) * 8;
        short8 vh = *(const short8*)&Hs[srow * 264 + scol];
        size_t off = ((size_t)kc * NTB + (r0 >> 4) + tl) * 512 + lane * 8;
        *(short8*)&Bh[off] = vh;
    }
}

// MEGA-KERNEL: A-stationary MFMA scorer + fused A-conversion + fused gather/
// loss/usage/output. Block = 128 rows x ALL 2048 codes, 4 waves x 32 rows.
// A converted raw fp32 -> bf16 fragments in-register (rows owned exclusively).
// B chunk = 64 cols full-K (32 KB) double-buffered in LDS (64 KB), 32 stages.
__global__ __launch_bounds__(256) void score_fused_kernel(const float* __restrict__ flat,
                                                          const unsigned short* __restrict__ Bh,
                                                          const float* __restrict__ cp,
                                                          const float* __restrict__ Q,
                                                          float* __restrict__ out) {
    __shared__ __align__(16) unsigned short Blds[2][32 * 512];  // 64 KB
    __shared__ int ksel[128];
    const int t = threadIdx.x, lane = t & 63, w = t >> 6;
    const int m0 = blockIdx.x * 128;
    const int fr = lane & 15, qr = lane >> 4;

    // A fragments from raw fp32 (one-time): af[kc][mt], lane holds
    // row = w*32 + mt*16 + fr, cols kc*32 + qr*8 .. +8
    short8 af[8][2];
#pragma unroll
    for (int kc = 0; kc < 8; kc++)
#pragma unroll
        for (int mt = 0; mt < 2; mt++) {
            int row = m0 + w * 32 + mt * 16 + fr;
            const float* p = flat + (size_t)row * DIN + kc * 32 + qr * 8;
            float4 a = *(const float4*)p;
            float4 b = *(const float4*)(p + 4);
            float f[8] = {a.x, a.y, a.z, a.w, b.x, b.y, b.z, b.w};
            unsigned short* hp = (unsigned short*)&af[kc][mt];
#pragma unroll
            for (int j = 0; j < 8; j++) hp[j] = bf16rne(f[j]);
        }

    // prefetch stage 0: 32 tiles (kc*4+nt); thread stages tiles i*4+w, i=0..7
#pragma unroll
    for (int i = 0; i < 8; i++) {
        int tl = i * 4 + w;
        int kc = tl >> 2, nt = tl & 3;
        async_load16(Bh + ((size_t)kc * NTB + nt) * 512 + lane * 8,
                     &Blds[0][tl * 512 + lane * 8]);
    }
    __syncthreads();

    float bestv[2][4];
    int besti[2][4];
#pragma unroll
    for (int mt = 0; mt < 2; mt++)
#pragma unroll
        for (int r = 0; r < 4; r++) { bestv[mt][r] = -3.4e38f; besti[mt][r] = 0; }

    const f32x4 ZERO4 = {0.f, 0.f, 0.f, 0.f};

#pragma unroll 1
    for (int s = 0; s < 32; s++) {
        const int cur = s & 1;
        if (s < 31) {
            const int nxt = cur ^ 1;
#pragma unroll
            for (int i = 0; i < 8; i++) {
                int tl = i * 4 + w;
                int kc = tl >> 2, nt = tl & 3;
                async_load16(Bh + ((size_t)kc * NTB + (s + 1) * 4 + nt) * 512 + lane * 8,
                             &Blds[nxt][tl * 512 + lane * 8]);
            }
        }
        f32x4 acc[2][4];
        {   // kc = 0: C = 0 operand (no acc init pass)
            short8 bf[4];
#pragma unroll
            for (int nt = 0; nt < 4; nt++)
                bf[nt] = *(const short8*)&Blds[cur][nt * 512 + lane * 8];
#pragma unroll
            for (int mt = 0; mt < 2; mt++)
#pragma unroll
                for (int nt = 0; nt < 4; nt++)
                    acc[mt][nt] = __builtin_amdgcn_mfma_f32_16x16x32_bf16(af[0][mt], bf[nt], ZERO4, 0, 0, 0);
        }
#pragma unroll
        for (int kc = 1; kc < 8; kc++) {
            short8 bf[4];
#pragma unroll
            for (int nt = 0; nt < 4; nt++)
                bf[nt] = *(const short8*)&Blds[cur][(kc * 4 + nt) * 512 + lane * 8];
#pragma unroll
            for (int mt = 0; mt < 2; mt++)
#pragma unroll
                for (int nt = 0; nt < 4; nt++)
                    acc[mt][nt] = __builtin_amdgcn_mfma_f32_16x16x32_bf16(af[kc][mt], bf[nt], acc[mt][nt], 0, 0, 0);
        }
        // epilogue: cols s*64 + nt*16 + fr
        const int base = s * 64 + fr;
        float cpv[4];
        int cidx[4];
#pragma unroll
        for (int nt = 0; nt < 4; nt++) { cpv[nt] = cp[base + nt * 16]; cidx[nt] = base + nt * 16; }
#pragma unroll
        for (int mt = 0; mt < 2; mt++)
#pragma unroll
            for (int r = 0; r < 4; r++) {
                float v = acc[mt][0][r] + cpv[0];
                int ci = cidx[0];
#pragma unroll
                for (int nt = 1; nt < 4; nt++) {
                    float vi = acc[mt][nt][r] + cpv[nt];
                    if (vi > v) { v = vi; ci = cidx[nt]; }   // asc nt: ties -> lower
                }
                if (v > bestv[mt][r]) { bestv[mt][r] = v; besti[mt][r] = ci; }  // asc s
            }
        __syncthreads();
    }

    // cross-fr argmax reduce (within 16-lane groups), tie -> lower idx
#pragma unroll
    for (int mt = 0; mt < 2; mt++)
#pragma unroll
        for (int r = 0; r < 4; r++) {
            float bv = bestv[mt][r];
            int bc = besti[mt][r];
#pragma unroll
            for (int xm = 1; xm < 16; xm <<= 1) {
                float ov = __shfl_xor(bv, xm, 64);
                int oc = __shfl_xor(bc, xm, 64);
                if (ov > bv || (ov == bv && oc < bc)) { bv = ov; bc = oc; }
            }
            if (fr == 0) ksel[w * 32 + mt * 16 + qr * 4 + r] = bc;
        }
    __syncthreads();

    // fused gather: wave w handles its own 32 rows
    float lsum = 0.0f;
    for (int rr = 0; rr < 32; rr++) {
        int rl = w * 32 + rr;
        int row = m0 + rl;
        int k = ksel[rl];                       // same-address broadcast
        const float* qr_ = Q + (size_t)k * DIN;
        const float* xr = flat + (size_t)row * DIN;
        float* ob = out + 1 + (size_t)row * DIN;
#pragma unroll
        for (int cc = 0; cc < 4; cc++) {
            int j = lane + 64 * cc;
            float q = qr_[j];
            float d = q - xr[j];
            lsum += d * d;
            ob[j] = q;
        }
        if (lane == 0) atomicAdd(out + 1 + TOK * DIN + k, 1.0f / (float)TOK);
    }
#pragma unroll
    for (int off = 32; off; off >>= 1) lsum += __shfl_down(lsum, off, 64);
    if (lane == 0) atomicAdd(out, lsum * (1.25f / (float)((size_t)TOK * DIN)));
}

extern "C" void kernel_launch(void* const* d_in, const int* in_sizes, int n_in,
                              void* d_out, int out_size, void* d_ws, size_t ws_size,
                              hipStream_t stream) {
    const float* inputs = (const float*)d_in[0];
    const float* bn1_gamma = (const float*)d_in[1];
    const float* bn1_beta  = (const float*)d_in[2];
    const float* W1 = (const float*)d_in[3];
    const float* b1 = (const float*)d_in[4];
    const float* E  = (const float*)d_in[5];
    const float* bn2_gamma = (const float*)d_in[6];
    const float* bn2_beta  = (const float*)d_in[7];
    const float* W2 = (const float*)d_in[8];
    const float* b2 = (const float*)d_in[9];

    float* ws = (float*)d_ws;
    float* Mp  = ws + OFF_MP;
    float* cp  = ws + OFF_CP;
    float* Q   = ws + OFF_Q;
    float* W2T = ws + OFF_W2T;
    float* u   = ws + OFF_U;
    float* cQ  = ws + OFF_CQ;
    unsigned short* Bh = (unsigned short*)(ws + OFF_BH);
    float* out = (float*)d_out;

    hipLaunchKernelGGL(prep1_kernel, dim3(768), dim3(256), 0, stream,
                       W1, W2, bn1_beta, bn2_gamma, bn2_beta, b2, W2T, u, cQ, out);
    hipLaunchKernelGGL(prep2_kernel, dim3(512), dim3(256), 0, stream,
                       E, W1, W2T, bn1_gamma, cQ, b1, u, Mp, Q, cp);
    hipLaunchKernelGGL(packB_kernel, dim3(64), dim3(256), 0, stream, Mp, Bh);
    hipLaunchKernelGGL(score_fused_kernel, dim3(512), dim3(256), 0, stream,
                       inputs, Bh, cp, Q, out);
}